// Round 4
// baseline (108.840 us; speedup 1.0000x reference)
//
#include <hip/hip_runtime.h>
#include <hip/hip_bf16.h>

// Problem constants
#define L1C 513
#define EMBC 64
#define VC 6
#define BC 128
#define NCOLS (L1C * VC)                  // 3078
#define NTC 64                            // n-columns per block tile
#define NTILES ((NCOLS + NTC - 1) / NTC)  // 49
#define CSC 12                            // s per chunk
#define NCHUNK ((L1C + CSC - 1) / CSC)    // 43

#define XELEMS ((size_t)L1C * BC * EMBC)  // bf16 elements in X
#define XBYTES (XELEMS * 2)               // 8,404,992 (16B aligned)
#define OUTELEMS ((size_t)BC * NCOLS)     // 393,984
#define PARTBYTES (OUTELEMS * 2)          // bf16 partials per chunk

typedef __attribute__((ext_vector_type(8))) short short8;
typedef __attribute__((ext_vector_type(4))) float f32x4;

__device__ __forceinline__ unsigned int pack_bf16x2(float a, float b) {
    __hip_bfloat16 ha = __float2bfloat16(a);
    __hip_bfloat16 hb = __float2bfloat16(b);
    unsigned short ua, ub;
    __builtin_memcpy(&ua, &ha, 2);
    __builtin_memcpy(&ub, &hb, 2);
    return (unsigned int)ua | ((unsigned int)ub << 16);
}

__device__ __forceinline__ unsigned short bf16bits(float a) {
    __hip_bfloat16 h = __float2bfloat16(a);
    unsigned short u;
    __builtin_memcpy(&u, &h, 2);
    return u;
}

// out[b][v][t] = bias[t][v]   (atomic-fallback path only)
__global__ void init_out_kernel(float* __restrict__ out, const float* __restrict__ bias) {
    int i = blockIdx.x * 256 + threadIdx.x;
    if (i >= (int)OUTELEMS) return;
    int r = i % NCOLS;
    int v = r / L1C;
    int t = r - v * L1C;
    out[i] = bias[t * VC + v];
}

// X[s][b][w] = bf16(emb[src[b,s], w]), linear layout
__global__ void build_x_kernel(const int* __restrict__ src, const float* __restrict__ emb,
                               unsigned short* __restrict__ X) {
    const int s = blockIdx.x;
    const int b = threadIdx.x >> 1;
    const int half = threadIdx.x & 1;
    const int tok = src[b * L1C + s];
    const float2* e = (const float2*)(emb + tok * EMBC + half * 32);
    unsigned int* row = (unsigned int*)(X + ((size_t)s * BC + b) * EMBC) + half * 16;
#pragma unroll
    for (int i = 0; i < 16; ++i) {
        float2 f = e[i];
        row[i] = pack_bf16x2(f.x, f.y);
    }
}

// Per (n-tile, s-chunk) block: C[128 x 64] = sum_{s in chunk, s>=t} X_s(128x64) @ W_s(64x64)
// 2-deep W register pipeline + 2-deep A prefetch; one barrier per s.
// SGPR-uniform bases + 32-bit per-lane offsets to keep VGPR <= 128 (4 blocks/CU).
template <bool PARTIAL>
__global__ __launch_bounds__(256, 4) void gemm_tril_kernel(
    const float* __restrict__ Wt, const unsigned short* __restrict__ X,
    void* __restrict__ outp, int CS) {
    const int tile = blockIdx.x;
    const int chunk = blockIdx.y;
    const int n0 = tile * NTC;
    const int s0 = chunk * CS;
    const int sEnd = min(s0 + CS, L1C);

    __shared__ __align__(16) unsigned short Blds[2][NTC * EMBC];  // 2 x 8KB

    const int tid = threadIdx.x;
    const int wid = tid >> 6;
    const int lane = tid & 63;
    const int l15 = lane & 15;
    const int h = lane >> 4;

    const int n = n0 + lane;
    const int tcol = n / VC;  // pad columns (n>=NCOLS) give tcol>=513 -> always masked
    const int nsafe = (n < NCOLS) ? n : (NCOLS - 1);
    const int wrow0 = wid * 16;
    const int wswz = (lane & 7) << 4;
    const int woff = wrow0 * NCOLS + nsafe;                      // per-lane, fits 32-bit
    const int xoff0 = (wid * 32 + l15) * EMBC + h * 8;           // A-frag element offsets
    const int xoff1 = (wid * 32 + 16 + l15) * EMBC + h * 8;

    f32x4 acc[2][4];
#pragma unroll
    for (int i = 0; i < 2; ++i)
#pragma unroll
        for (int j = 0; j < 4; ++j) acc[i][j] = f32x4{0.f, 0.f, 0.f, 0.f};

    const int sBeg = max(s0, n0 / VC);

#define ISSUEW(ss, farr)                                                   \
    {                                                                      \
        const int scl_ = ((ss) < L1C) ? (ss) : (L1C - 1);                  \
        const float* wb_ = Wt + (size_t)scl_ * (EMBC * NCOLS);             \
        _Pragma("unroll") for (int u_ = 0; u_ < 16; ++u_)                  \
            farr[u_] = wb_[woff + u_ * NCOLS];                             \
    }

#define PACKW(ss, farr, buf)                                                     \
    {                                                                            \
        const bool act_ = (tcol <= (ss));                                        \
        char* dr_ = (char*)Blds[buf] + lane * 128;                               \
        _Pragma("unroll") for (int u_ = 0; u_ < 4; ++u_) {                       \
            float g0 = act_ ? farr[u_ * 4 + 0] : 0.f;                            \
            float g1 = act_ ? farr[u_ * 4 + 1] : 0.f;                            \
            float g2 = act_ ? farr[u_ * 4 + 2] : 0.f;                            \
            float g3 = act_ ? farr[u_ * 4 + 3] : 0.f;                            \
            uint2 pk_ = make_uint2(pack_bf16x2(g0, g1), pack_bf16x2(g2, g3));    \
            *(uint2*)(dr_ + ((2 * (wrow0 + u_ * 4)) ^ wswz)) = pk_;              \
        }                                                                        \
    }

#define ISSUEA(ss, aarr)                                                   \
    {                                                                      \
        const int scl_ = ((ss) < L1C) ? (ss) : (L1C - 1);                  \
        const unsigned short* xr_ = X + (size_t)scl_ * (BC * EMBC);        \
        aarr[0] = *(const short8*)(xr_ + xoff0);                           \
        aarr[1] = *(const short8*)(xr_ + xoff0 + 32);                      \
        aarr[2] = *(const short8*)(xr_ + xoff1);                           \
        aarr[3] = *(const short8*)(xr_ + xoff1 + 32);                      \
    }

#define MFMASTEP(aarr, buf)                                                                              \
    {                                                                                                    \
        _Pragma("unroll") for (int kk_ = 0; kk_ < 2; ++kk_) {                                            \
            const int foff_ = (kk_ * 64 + h * 16) ^ ((l15 & 7) << 4);                                    \
            _Pragma("unroll") for (int nt_ = 0; nt_ < 4; ++nt_) {                                        \
                short8 bb_ = *(const short8*)((const char*)Blds[buf] + (nt_ * 16 + l15) * 128 + foff_);  \
                acc[0][nt_] = __builtin_amdgcn_mfma_f32_16x16x32_bf16(aarr[kk_], bb_, acc[0][nt_], 0, 0, 0);     \
                acc[1][nt_] = __builtin_amdgcn_mfma_f32_16x16x32_bf16(aarr[2 + kk_], bb_, acc[1][nt_], 0, 0, 0); \
            }                                                                                            \
        }                                                                                                \
    }

    if (sBeg < sEnd) {
        float fW0[16], fW1[16];
        short8 aC[4], aN[4];
        // prologue: stage B(sBeg) via fW1's storage; then fill the 2-deep pipe
        ISSUEW(sBeg, fW1);
        PACKW(sBeg, fW1, 0);
        ISSUEW(sBeg + 1, fW0);
        ISSUEA(sBeg, aC);
        __syncthreads();

        int s = sBeg, cur = 0;
        while (true) {
            // even iter: consume fW0/aC, issue fW1/aN
            ISSUEW(s + 2, fW1);
            ISSUEA(s + 1, aN);
            MFMASTEP(aC, cur);
            PACKW(s + 1, fW0, cur ^ 1);
            __syncthreads();
            cur ^= 1;
            if (++s >= sEnd) break;

            // odd iter: consume fW1/aN, issue fW0/aC
            ISSUEW(s + 2, fW0);
            ISSUEA(s + 1, aC);
            MFMASTEP(aN, cur);
            PACKW(s + 1, fW1, cur ^ 1);
            __syncthreads();
            cur ^= 1;
            if (++s >= sEnd) break;
        }
    }

    // epilogue — C/D layout (verified): col = l15 (n), row-in-16 = h*4 + reg
#pragma unroll
    for (int nt = 0; nt < 4; ++nt) {
        const int nn = n0 + nt * 16 + l15;
        if (nn >= NCOLS) continue;
        if (PARTIAL) {
            unsigned short* dst = (unsigned short*)outp + (size_t)chunk * OUTELEMS;
#pragma unroll
            for (int ms = 0; ms < 2; ++ms)
#pragma unroll
                for (int r = 0; r < 4; ++r) {
                    const int bi = wid * 32 + ms * 16 + h * 4 + r;
                    dst[(size_t)bi * NCOLS + nn] = bf16bits(acc[ms][nt][r]);
                }
        } else {
            float* dst = (float*)outp;
            const int t = nn / VC;
            const int v = nn - t * VC;
            const size_t obase = (size_t)v * L1C + t;
#pragma unroll
            for (int ms = 0; ms < 2; ++ms)
#pragma unroll
                for (int r = 0; r < 4; ++r) {
                    const int bi = wid * 32 + ms * 16 + h * 4 + r;
                    atomicAdd(dst + (size_t)bi * NCOLS + obase, acc[ms][nt][r]);
                }
        }
    }
#undef ISSUEW
#undef PACKW
#undef ISSUEA
#undef MFMASTEP
}

// out[b][v][t] = bias[n] + sum_c bf16 partial[c][b][n],  n = t*6+v
__global__ void reduce_kernel(const unsigned short* __restrict__ partial,
                              const float* __restrict__ bias,
                              float* __restrict__ out, int nchunks) {
    int i4 = blockIdx.x * 256 + threadIdx.x;
    if (i4 >= (int)(OUTELEMS / 4)) return;
    const size_t base = (size_t)i4 * 4;
    float sum[4];
#pragma unroll
    for (int j = 0; j < 4; ++j) {
        int idx = (int)base + j;
        sum[j] = bias[idx % NCOLS];
    }
    for (int c = 0; c < nchunks; ++c) {
        const ushort4 p = *(const ushort4*)(partial + (size_t)c * OUTELEMS + base);
        unsigned int u0 = (unsigned int)p.x << 16, u1 = (unsigned int)p.y << 16;
        unsigned int u2 = (unsigned int)p.z << 16, u3 = (unsigned int)p.w << 16;
        float f0, f1, f2, f3;
        __builtin_memcpy(&f0, &u0, 4);
        __builtin_memcpy(&f1, &u1, 4);
        __builtin_memcpy(&f2, &u2, 4);
        __builtin_memcpy(&f3, &u3, 4);
        sum[0] += f0;
        sum[1] += f1;
        sum[2] += f2;
        sum[3] += f3;
    }
#pragma unroll
    for (int j = 0; j < 4; ++j) {
        int idx = (int)base + j;
        int b = idx / NCOLS;
        int nn = idx - b * NCOLS;
        int t = nn / VC;
        int v = nn - t * VC;
        out[(size_t)b * NCOLS + (size_t)v * L1C + t] = sum[j];
    }
}

extern "C" void kernel_launch(void* const* d_in, const int* in_sizes, int n_in,
                              void* d_out, int out_size, void* d_ws, size_t ws_size,
                              hipStream_t stream) {
    const int* src = (const int*)d_in[0];
    const float* emb = (const float*)d_in[1];
    const float* wt = (const float*)d_in[2];
    const float* bias = (const float*)d_in[3];
    float* out = (float*)d_out;
    unsigned short* X = (unsigned short*)d_ws;

    build_x_kernel<<<L1C, 256, 0, stream>>>(src, emb, X);

    size_t avail = (ws_size > XBYTES) ? (ws_size - XBYTES) : 0;
    int nchunks = (int)(avail / PARTBYTES);
    if (nchunks > NCHUNK) nchunks = NCHUNK;  // CS=12 target

    if (nchunks >= 2) {
        int CS = (L1C + nchunks - 1) / nchunks;
        nchunks = (L1C + CS - 1) / CS;
        unsigned short* partial = (unsigned short*)((char*)d_ws + XBYTES);
        dim3 grid(NTILES, nchunks);
        gemm_tril_kernel<true><<<grid, 256, 0, stream>>>(wt, X, (void*)partial, CS);
        reduce_kernel<<<(int)((OUTELEMS / 4 + 255) / 256), 256, 0, stream>>>(partial, bias, out, nchunks);
    } else {
        // scratch too small: atomic fallback
        init_out_kernel<<<(int)((OUTELEMS + 255) / 256), 256, 0, stream>>>(out, bias);
        dim3 grid(NTILES, 17);
        gemm_tril_kernel<false><<<grid, 256, 0, stream>>>(wt, X, (void*)out, 31);
    }
}

// Round 5
// 93.986 us; speedup vs baseline: 1.1580x; 1.1580x over previous
//
#include <hip/hip_runtime.h>
#include <hip/hip_bf16.h>

// Problem constants
#define L1C 513
#define EMBC 64
#define VC 6
#define BC 128
#define NCOLS (L1C * VC)                  // 3078
#define NTC 64                            // n-columns per block tile
#define NTILES ((NCOLS + NTC - 1) / NTC)  // 49

#define XELEMS ((size_t)L1C * BC * EMBC)  // bf16 elements in X
#define XBYTES (XELEMS * 2)               // 8,404,992 (16B aligned)
#define OUTELEMS ((size_t)BC * NCOLS)     // 393,984
#define PARTBYTES (OUTELEMS * 2)          // bf16 partials per chunk

typedef __attribute__((ext_vector_type(8))) short short8;
typedef __attribute__((ext_vector_type(4))) float f32x4;

__device__ __forceinline__ unsigned int pack_bf16x2(float a, float b) {
    __hip_bfloat16 ha = __float2bfloat16(a);
    __hip_bfloat16 hb = __float2bfloat16(b);
    unsigned short ua, ub;
    __builtin_memcpy(&ua, &ha, 2);
    __builtin_memcpy(&ub, &hb, 2);
    return (unsigned int)ua | ((unsigned int)ub << 16);
}

__device__ __forceinline__ unsigned short bf16bits(float a) {
    __hip_bfloat16 h = __float2bfloat16(a);
    unsigned short u;
    __builtin_memcpy(&u, &h, 2);
    return u;
}

// out[b][v][t] = bias[t][v]   (atomic-fallback path only)
__global__ void init_out_kernel(float* __restrict__ out, const float* __restrict__ bias) {
    int i = blockIdx.x * 256 + threadIdx.x;
    if (i >= (int)OUTELEMS) return;
    int r = i % NCOLS;
    int v = r / L1C;
    int t = r - v * L1C;
    out[i] = bias[t * VC + v];
}

// X[s][b][w] = bf16(emb[src[b,s], w]), linear layout
__global__ void build_x_kernel(const int* __restrict__ src, const float* __restrict__ emb,
                               unsigned short* __restrict__ X) {
    const int s = blockIdx.x;
    const int b = threadIdx.x >> 1;
    const int half = threadIdx.x & 1;
    const int tok = src[b * L1C + s];
    const float2* e = (const float2*)(emb + tok * EMBC + half * 32);
    unsigned int* row = (unsigned int*)(X + ((size_t)s * BC + b) * EMBC) + half * 16;
#pragma unroll
    for (int i = 0; i < 16; ++i) {
        float2 f = e[i];
        row[i] = pack_bf16x2(f.x, f.y);
    }
}

// Per (n-tile, s-chunk) block: C[128 x 64] = sum_{s in chunk, s>=t} X_s(128x64) @ W_s(64x64)
// 2-deep W register pipeline + 1-deep A prefetch; ONE raw barrier per s with
// lgkmcnt-only drain (T4): in-flight global loads legally cross the barrier.
template <bool PARTIAL>
__global__ __launch_bounds__(256) void gemm_tril_kernel(
    const float* __restrict__ Wt, const unsigned short* __restrict__ X,
    void* __restrict__ outp, int CS) {
    const int tile = blockIdx.x;
    const int chunk = blockIdx.y;
    const int n0 = tile * NTC;
    const int s0 = chunk * CS;
    const int sEnd = min(s0 + CS, L1C);

    __shared__ __align__(16) unsigned short Blds[2][NTC * EMBC];  // 2 x 8KB

    const int tid = threadIdx.x;
    const int wid = tid >> 6;
    const int lane = tid & 63;
    const int l15 = lane & 15;
    const int h = lane >> 4;

    const int n = n0 + lane;
    const int tcol = n / VC;  // pad columns (n>=NCOLS) give tcol>=513 -> always masked
    const size_t nsafe = (n < NCOLS) ? (size_t)n : (size_t)(NCOLS - 1);
    const int wrow0 = wid * 16;
    const int wswz = (lane & 7) << 4;

    f32x4 acc[2][4];
#pragma unroll
    for (int i = 0; i < 2; ++i)
#pragma unroll
        for (int j = 0; j < 4; ++j) acc[i][j] = f32x4{0.f, 0.f, 0.f, 0.f};

    const int sBeg = max(s0, n0 / VC);

// Raw barrier: drain LDS ops only; leave global loads in flight (counted vmcnt
// waits are auto-inserted at each register use). sched_barrier(0) pins order.
#define SYNCB()                                                \
    {                                                          \
        __builtin_amdgcn_sched_barrier(0);                     \
        asm volatile("s_waitcnt lgkmcnt(0)" ::: "memory");     \
        __builtin_amdgcn_s_barrier();                          \
        __builtin_amdgcn_sched_barrier(0);                     \
    }

#define ISSUEW(ss, farr)                                                         \
    {                                                                            \
        const int scl_ = ((ss) < L1C) ? (ss) : (L1C - 1);                        \
        const float* wb_ = Wt + ((size_t)scl_ * EMBC + wrow0) * NCOLS + nsafe;   \
        _Pragma("unroll") for (int u_ = 0; u_ < 16; ++u_)                        \
            farr[u_] = wb_[(size_t)u_ * NCOLS];                                  \
    }

#define PACKW(ss, farr, buf)                                                     \
    {                                                                            \
        const bool act_ = (tcol <= (ss));                                        \
        char* dr_ = (char*)Blds[buf] + lane * 128;                               \
        _Pragma("unroll") for (int u_ = 0; u_ < 4; ++u_) {                       \
            float g0 = act_ ? farr[u_ * 4 + 0] : 0.f;                            \
            float g1 = act_ ? farr[u_ * 4 + 1] : 0.f;                            \
            float g2 = act_ ? farr[u_ * 4 + 2] : 0.f;                            \
            float g3 = act_ ? farr[u_ * 4 + 3] : 0.f;                            \
            uint2 pk_ = make_uint2(pack_bf16x2(g0, g1), pack_bf16x2(g2, g3));    \
            *(uint2*)(dr_ + ((2 * (wrow0 + u_ * 4)) ^ wswz)) = pk_;              \
        }                                                                        \
    }

#define ISSUEA(ss, aarr)                                                             \
    {                                                                                \
        const int scl_ = ((ss) < L1C) ? (ss) : (L1C - 1);                            \
        const unsigned short* xr_ = X + (size_t)scl_ * (BC * EMBC);                  \
        aarr[0] = *(const short8*)(xr_ + (wid * 32 + l15) * EMBC + h * 8);           \
        aarr[1] = *(const short8*)(xr_ + (wid * 32 + l15) * EMBC + 32 + h * 8);      \
        aarr[2] = *(const short8*)(xr_ + (wid * 32 + 16 + l15) * EMBC + h * 8);      \
        aarr[3] = *(const short8*)(xr_ + (wid * 32 + 16 + l15) * EMBC + 32 + h * 8); \
    }

#define MFMASTEP(aarr, buf)                                                                              \
    {                                                                                                    \
        _Pragma("unroll") for (int kk_ = 0; kk_ < 2; ++kk_) {                                            \
            const int foff_ = (kk_ * 64 + h * 16) ^ ((l15 & 7) << 4);                                    \
            _Pragma("unroll") for (int nt_ = 0; nt_ < 4; ++nt_) {                                        \
                short8 bb_ = *(const short8*)((const char*)Blds[buf] + (nt_ * 16 + l15) * 128 + foff_);  \
                acc[0][nt_] = __builtin_amdgcn_mfma_f32_16x16x32_bf16(aarr[kk_], bb_, acc[0][nt_], 0, 0, 0);     \
                acc[1][nt_] = __builtin_amdgcn_mfma_f32_16x16x32_bf16(aarr[2 + kk_], bb_, acc[1][nt_], 0, 0, 0); \
            }                                                                                            \
        }                                                                                                \
    }

    if (sBeg < sEnd) {
        float fW0[16], fW1[16];
        short8 aC[4], aN[4];
        // prologue: stage B(sBeg) via fW1's storage; then fill the 2-deep pipe
        ISSUEW(sBeg, fW1);
        PACKW(sBeg, fW1, 0);
        ISSUEW(sBeg + 1, fW0);
        ISSUEA(sBeg, aC);
        SYNCB();

        int s = sBeg, cur = 0;
        while (true) {
            // even iter: consume fW0/aC, issue fW1/aN
            ISSUEW(s + 2, fW1);
            ISSUEA(s + 1, aN);
            MFMASTEP(aC, cur);
            PACKW(s + 1, fW0, cur ^ 1);
            SYNCB();
            cur ^= 1;
            if (++s >= sEnd) break;

            // odd iter: consume fW1/aN, issue fW0/aC
            ISSUEW(s + 2, fW0);
            ISSUEA(s + 1, aC);
            MFMASTEP(aN, cur);
            PACKW(s + 1, fW1, cur ^ 1);
            SYNCB();
            cur ^= 1;
            if (++s >= sEnd) break;
        }
    }

    // epilogue — C/D layout (verified): col = l15 (n), row-in-16 = h*4 + reg
#pragma unroll
    for (int nt = 0; nt < 4; ++nt) {
        const int nn = n0 + nt * 16 + l15;
        if (nn >= NCOLS) continue;
        if (PARTIAL) {
            unsigned short* dst = (unsigned short*)outp + (size_t)chunk * OUTELEMS;
#pragma unroll
            for (int ms = 0; ms < 2; ++ms)
#pragma unroll
                for (int r = 0; r < 4; ++r) {
                    const int bi = wid * 32 + ms * 16 + h * 4 + r;
                    dst[(size_t)bi * NCOLS + nn] = bf16bits(acc[ms][nt][r]);
                }
        } else {
            float* dst = (float*)outp;
            const int t = nn / VC;
            const int v = nn - t * VC;
            const size_t obase = (size_t)v * L1C + t;
#pragma unroll
            for (int ms = 0; ms < 2; ++ms)
#pragma unroll
                for (int r = 0; r < 4; ++r) {
                    const int bi = wid * 32 + ms * 16 + h * 4 + r;
                    atomicAdd(dst + (size_t)bi * NCOLS + obase, acc[ms][nt][r]);
                }
        }
    }
#undef SYNCB
#undef ISSUEW
#undef PACKW
#undef ISSUEA
#undef MFMASTEP
}

// out[b][v][t] = bias[n] + sum_c bf16 partial[c][b][n],  n = t*6+v
__global__ void reduce_kernel(const unsigned short* __restrict__ partial,
                              const float* __restrict__ bias,
                              float* __restrict__ out, int nchunks) {
    int i4 = blockIdx.x * 256 + threadIdx.x;
    if (i4 >= (int)(OUTELEMS / 4)) return;
    const size_t base = (size_t)i4 * 4;
    float sum[4];
#pragma unroll
    for (int j = 0; j < 4; ++j) {
        int idx = (int)base + j;
        sum[j] = bias[idx % NCOLS];
    }
    for (int c = 0; c < nchunks; ++c) {
        const ushort4 p = *(const ushort4*)(partial + (size_t)c * OUTELEMS + base);
        unsigned int u0 = (unsigned int)p.x << 16, u1 = (unsigned int)p.y << 16;
        unsigned int u2 = (unsigned int)p.z << 16, u3 = (unsigned int)p.w << 16;
        float f0, f1, f2, f3;
        __builtin_memcpy(&f0, &u0, 4);
        __builtin_memcpy(&f1, &u1, 4);
        __builtin_memcpy(&f2, &u2, 4);
        __builtin_memcpy(&f3, &u3, 4);
        sum[0] += f0;
        sum[1] += f1;
        sum[2] += f2;
        sum[3] += f3;
    }
#pragma unroll
    for (int j = 0; j < 4; ++j) {
        int idx = (int)base + j;
        int b = idx / NCOLS;
        int nn = idx - b * NCOLS;
        int t = nn / VC;
        int v = nn - t * VC;
        out[(size_t)b * NCOLS + (size_t)v * L1C + t] = sum[j];
    }
}

extern "C" void kernel_launch(void* const* d_in, const int* in_sizes, int n_in,
                              void* d_out, int out_size, void* d_ws, size_t ws_size,
                              hipStream_t stream) {
    const int* src = (const int*)d_in[0];
    const float* emb = (const float*)d_in[1];
    const float* wt = (const float*)d_in[2];
    const float* bias = (const float*)d_in[3];
    float* out = (float*)d_out;
    unsigned short* X = (unsigned short*)d_ws;

    build_x_kernel<<<L1C, 256, 0, stream>>>(src, emb, X);

    size_t avail = (ws_size > XBYTES) ? (ws_size - XBYTES) : 0;
    int nchunks = (int)(avail / PARTBYTES);
    if (nchunks > 31) nchunks = 31;  // CS=17 (round-3 known-good)

    if (nchunks >= 2) {
        int CS = (L1C + nchunks - 1) / nchunks;
        nchunks = (L1C + CS - 1) / CS;
        unsigned short* partial = (unsigned short*)((char*)d_ws + XBYTES);
        dim3 grid(NTILES, nchunks);
        gemm_tril_kernel<true><<<grid, 256, 0, stream>>>(wt, X, (void*)partial, CS);
        reduce_kernel<<<(int)((OUTELEMS / 4 + 255) / 256), 256, 0, stream>>>(partial, bias, out, nchunks);
    } else {
        // scratch too small: atomic fallback
        init_out_kernel<<<(int)((OUTELEMS + 255) / 256), 256, 0, stream>>>(out, bias);
        dim3 grid(NTILES, 17);
        gemm_tril_kernel<false><<<grid, 256, 0, stream>>>(wt, X, (void*)out, 31);
    }
}